// Round 3
// baseline (2928.385 us; speedup 1.0000x reference)
//
#include <hip/hip_runtime.h>
#include <stdint.h>

// Problem dims (fixed)
#define Bq 8
#define Lq 4096
#define Dq 1024
#define Hq 64
#define Mq (Bq*Lq)   // 32768 rows

typedef short bf16x8 __attribute__((ext_vector_type(8)));  // 8 bf16 in 4 VGPRs
typedef float f32x4  __attribute__((ext_vector_type(4)));

__device__ __forceinline__ float b2f(unsigned short u) {
  union { unsigned int i; float f; } v; v.i = ((unsigned int)u) << 16; return v.f;
}
__device__ __forceinline__ unsigned short f2b(float f) {
  union { float f; unsigned int i; } v; v.f = f;
  unsigned int r = v.i + 0x7fffu + ((v.i >> 16) & 1u);  // RNE
  return (unsigned short)(r >> 16);
}
__device__ __forceinline__ bf16x8 pack8(float4 a, float4 b) {
  bf16x8 r;
  r[0] = (short)f2b(a.x); r[1] = (short)f2b(a.y); r[2] = (short)f2b(a.z); r[3] = (short)f2b(a.w);
  r[4] = (short)f2b(b.x); r[5] = (short)f2b(b.y); r[6] = (short)f2b(b.z); r[7] = (short)f2b(b.w);
  return r;
}

// ---------------- dtype classifier: is this buffer bf16 (1) or f32 (0)? ----------------
// Sample even-position u16s of a large random-normal weight buffer. If bf16 data,
// those are genuine bf16 values -> exponent field in a sane band (~100%). If f32
// data, they're low mantissa halves -> uniform bits (~43% in-band).
__global__ void classify_kernel(const unsigned short* __restrict__ w, unsigned int* flag) {
  __shared__ unsigned int s_nz, s_ib;
  if (threadIdx.x == 0) { s_nz = 0; s_ib = 0; }
  __syncthreads();
  unsigned int nz = 0, ib = 0;
  for (int i = threadIdx.x; i < 8192; i += 256) {
    unsigned short u = w[2 * i];
    if (u) {
      nz++;
      unsigned int e = (u >> 7) & 0xFFu;
      if (e >= 0x31u && e <= 0x9Du) ib++;
    }
  }
  atomicAdd(&s_nz, nz); atomicAdd(&s_ib, ib);
  __syncthreads();
  if (threadIdx.x == 0) *flag = (s_nz > 0 && 4u * s_ib >= 3u * s_nz) ? 1u : 0u;
}

// ---------------- ws-too-small sentinel: absmax ~= 1000 signals the branch ----------------
__global__ void sentinel_kernel(unsigned short* out, int n) {
  int i = blockIdx.x * 256 + threadIdx.x;
  if (i < n) out[i] = 0x447A;  // bf16 1000.0 (as f32 pairs reads ~1000.6)
}

// ---------------- LayerNorm: one block (256 thr) per row of 1024 ----------------
__global__ void ln_kernel(const void* __restrict__ xv,
                          const void* __restrict__ gv,
                          const void* __restrict__ bev,
                          unsigned short* __restrict__ xn,
                          const unsigned int* __restrict__ flagp) {
  const int isbf = (int)*flagp;
  const int row = blockIdx.x;
  const int t = threadIdx.x;
  const size_t base = (size_t)row * Dq;
  float v0, v1, v2, v3, g0, g1, g2, g3, e0, e1, e2, e3;
  if (isbf) {
    ushort4 u  = *(const ushort4*)((const unsigned short*)xv + base + t * 4);
    ushort4 g  = *(const ushort4*)((const unsigned short*)gv + t * 4);
    ushort4 be = *(const ushort4*)((const unsigned short*)bev + t * 4);
    v0 = b2f(u.x); v1 = b2f(u.y); v2 = b2f(u.z); v3 = b2f(u.w);
    g0 = b2f(g.x); g1 = b2f(g.y); g2 = b2f(g.z); g3 = b2f(g.w);
    e0 = b2f(be.x); e1 = b2f(be.y); e2 = b2f(be.z); e3 = b2f(be.w);
  } else {
    float4 u  = *(const float4*)((const float*)xv + base + t * 4);
    float4 g  = *(const float4*)((const float*)gv + t * 4);
    float4 be = *(const float4*)((const float*)bev + t * 4);
    v0 = u.x; v1 = u.y; v2 = u.z; v3 = u.w;
    g0 = g.x; g1 = g.y; g2 = g.z; g3 = g.w;
    e0 = be.x; e1 = be.y; e2 = be.z; e3 = be.w;
  }
  float s  = v0 + v1 + v2 + v3;
  float ss = v0*v0 + v1*v1 + v2*v2 + v3*v3;
#pragma unroll
  for (int off = 32; off >= 1; off >>= 1) {
    s  += __shfl_xor(s,  off, 64);
    ss += __shfl_xor(ss, off, 64);
  }
  __shared__ float sb[8];
  const int w = t >> 6, lane = t & 63;
  if (lane == 0) { sb[w] = s; sb[4 + w] = ss; }
  __syncthreads();
  s  = sb[0] + sb[1] + sb[2] + sb[3];
  ss = sb[4] + sb[5] + sb[6] + sb[7];
  const float mu   = s * (1.0f / Dq);
  const float var  = ss * (1.0f / Dq) - mu * mu;
  const float rstd = rsqrtf(var + 1e-5f);
  ushort4 o;
  o.x = f2b((v0 - mu) * rstd * g0 + e0);
  o.y = f2b((v1 - mu) * rstd * g1 + e1);
  o.z = f2b((v2 - mu) * rstd * g2 + e2);
  o.w = f2b((v3 - mu) * rstd * g3 + e3);
  *(ushort4*)(xn + base + t * 4) = o;
}

// ---------------- MFMA GEMM: out[m,n] = (sum_k A[m,k]*W[n,k] + bias[n])*scale (+resid) ----
// A is ALWAYS internal bf16 workspace. W/bias/resid are polymorphic via *flagp.
// out_mode: 0 = bf16, 1 = f32, 2 = follow flag (bf16 if isbf else f32).
__global__ void gemm_bt(const unsigned short* __restrict__ A,
                        const void* __restrict__ Wv,
                        const void* __restrict__ biasv,
                        const void* __restrict__ residv,
                        void* __restrict__ out,
                        int N, int K, float scale, int out_mode,
                        const unsigned int* __restrict__ flagp) {
  __shared__ unsigned short smA[128 * 32];
  __shared__ unsigned short smB[128 * 32];
  const int isbf = (int)*flagp;
  const int tid  = threadIdx.x;
  const int w    = tid >> 6;
  const int lane = tid & 63;
  const int wm   = w >> 1;
  const int wn   = w & 1;
  const int row0 = blockIdx.x * 128;
  const int col0 = blockIdx.y * 128;

  // staging chunk map: chunk c in [0,512): row=c>>2, kchunk=c&3 (8 elems each)
  const int c0 = tid, c1 = tid + 256;
  const int ar0 = row0 + (c0 >> 2), ak0 = (c0 & 3) * 8;
  const int ar1 = row0 + (c1 >> 2), ak1 = (c1 & 3) * 8;
  int br0 = col0 + (c0 >> 2), bk0 = (c0 & 3) * 8;
  int br1 = col0 + (c1 >> 2), bk1 = (c1 & 3) * 8;
  if (br0 >= N) br0 = N - 1;   // clamp (dup load, epilogue-masked)
  if (br1 >= N) br1 = N - 1;
  const size_t aro0 = (size_t)ar0 * K + ak0;
  const size_t aro1 = (size_t)ar1 * K + ak1;
  const size_t bro0 = (size_t)br0 * K + bk0;
  const size_t bro1 = (size_t)br1 * K + bk1;

  f32x4 acc[4][4];
#pragma unroll
  for (int i = 0; i < 4; ++i)
#pragma unroll
    for (int j = 0; j < 4; ++j) acc[i][j] = (f32x4){0.f, 0.f, 0.f, 0.f};

  const int mrow = lane & 15;
  const int kq8  = (lane >> 4) * 8;

  for (int k0 = 0; k0 < K; k0 += 32) {
    bf16x8 ta0 = *(const bf16x8*)(A + aro0 + k0);
    bf16x8 ta1 = *(const bf16x8*)(A + aro1 + k0);
    bf16x8 tb0, tb1;
    if (isbf) {
      const unsigned short* W = (const unsigned short*)Wv;
      tb0 = *(const bf16x8*)(W + bro0 + k0);
      tb1 = *(const bf16x8*)(W + bro1 + k0);
    } else {
      const float* W = (const float*)Wv;
      float4 w00 = *(const float4*)(W + bro0 + k0);
      float4 w01 = *(const float4*)(W + bro0 + k0 + 4);
      float4 w10 = *(const float4*)(W + bro1 + k0);
      float4 w11 = *(const float4*)(W + bro1 + k0 + 4);
      tb0 = pack8(w00, w01);
      tb1 = pack8(w10, w11);
    }
    __syncthreads();   // previous iteration's LDS reads complete before overwrite
    *(bf16x8*)(smA + c0 * 8) = ta0;
    *(bf16x8*)(smA + c1 * 8) = ta1;
    *(bf16x8*)(smB + c0 * 8) = tb0;
    *(bf16x8*)(smB + c1 * 8) = tb1;
    __syncthreads();
    bf16x8 a[4], bb[4];
#pragma unroll
    for (int mt = 0; mt < 4; ++mt)
      a[mt] = *(const bf16x8*)(smA + (wm * 64 + mt * 16 + mrow) * 32 + kq8);
#pragma unroll
    for (int nt = 0; nt < 4; ++nt)
      bb[nt] = *(const bf16x8*)(smB + (wn * 64 + nt * 16 + mrow) * 32 + kq8);
#pragma unroll
    for (int mt = 0; mt < 4; ++mt)
#pragma unroll
      for (int nt = 0; nt < 4; ++nt)
        acc[mt][nt] = __builtin_amdgcn_mfma_f32_16x16x32_bf16(a[mt], bb[nt], acc[mt][nt], 0, 0, 0);
  }

  // epilogue: C/D layout col=lane&15, row=(lane>>4)*4+reg
  const int colL = lane & 15;
  const int rq   = lane >> 4;
  const int wf32 = (out_mode == 1) || (out_mode == 2 && !isbf);
#pragma unroll
  for (int nt = 0; nt < 4; ++nt) {
    const int col = col0 + wn * 64 + nt * 16 + colL;
    if (col >= N) continue;
    const float bv = isbf ? b2f(((const unsigned short*)biasv)[col])
                          : ((const float*)biasv)[col];
#pragma unroll
    for (int mt = 0; mt < 4; ++mt) {
      const int rowb = row0 + wm * 64 + mt * 16 + rq * 4;
#pragma unroll
      for (int r = 0; r < 4; ++r) {
        const int row = rowb + r;
        const size_t idx = (size_t)row * N + col;
        float val = (acc[mt][nt][r] + bv) * scale;
        if (residv) val += isbf ? b2f(((const unsigned short*)residv)[idx])
                                : ((const float*)residv)[idx];
        if (wf32) ((float*)out)[idx] = val;
        else ((unsigned short*)out)[idx] = f2b(val);
      }
    }
  }
}

// ---------------- Sequential mLSTM scan: one wave per (b,h) ----------------
// lane: e = lane&15 (k/output index), d = (lane>>4)*4 + r (v/q index); C[d][e] 4/lane.
__global__ void scan_kernel(const unsigned short* __restrict__ q,
                            const unsigned short* __restrict__ k,
                            const unsigned short* __restrict__ v,
                            const float* __restrict__ it_arr,
                            const float* __restrict__ ft_arr,
                            unsigned short* __restrict__ hout) {
  const int bh = blockIdx.x;
  const int b  = bh >> 6;
  const int h  = bh & 63;
  const int lane = threadIdx.x;
  const int e  = lane & 15;
  const int dg = lane >> 4;
  const int d0 = dg * 4;
  const size_t base0 = ((size_t)b * Lq) * Dq + (size_t)h * 16;
  const size_t gbase = ((size_t)b * Lq) * Hq + h;

  float C0 = 0, C1 = 0, C2 = 0, C3 = 0;
  float n0 = 0, n1 = 0, n2 = 0, n3 = 0;
  float m = 0.f;

  unsigned short ke_c = k[base0 + e];
  ushort4 ku_c = *(const ushort4*)(k + base0 + d0);
  ushort4 qu_c = *(const ushort4*)(q + base0 + d0);
  ushort4 vu_c = *(const ushort4*)(v + base0 + d0);
  float it_c = it_arr[gbase];
  float ft_c = ft_arr[gbase];

  for (int t = 0; t < Lq; ++t) {
    unsigned short ke_n = 0; ushort4 ku_n = {0,0,0,0}, qu_n = {0,0,0,0}, vu_n = {0,0,0,0};
    float it_n = 0.f, ft_n = 0.f;
    if (t + 1 < Lq) {
      const size_t pn = base0 + (size_t)(t + 1) * Dq;
      ke_n = k[pn + e];
      ku_n = *(const ushort4*)(k + pn + d0);
      qu_n = *(const ushort4*)(q + pn + d0);
      vu_n = *(const ushort4*)(v + pn + d0);
      it_n = it_arr[gbase + (size_t)(t + 1) * Hq];
      ft_n = ft_arr[gbase + (size_t)(t + 1) * Hq];
    }
    const float fm = ft_c + m;
    const float mn = fmaxf(fm, it_c);
    const float fg = __expf(fm - mn);   // <= 1
    const float ig = __expf(it_c - mn); // <= 1
    m = mn;
    const float ke  = b2f(ke_c);
    const float k0f = b2f(ku_c.x), k1f = b2f(ku_c.y), k2f = b2f(ku_c.z), k3f = b2f(ku_c.w);
    const float q0f = b2f(qu_c.x), q1f = b2f(qu_c.y), q2f = b2f(qu_c.z), q3f = b2f(qu_c.w);
    const float v0f = b2f(vu_c.x), v1f = b2f(vu_c.y), v2f = b2f(vu_c.z), v3f = b2f(vu_c.w);
    const float a = ig * ke;
    C0 = fmaf(fg, C0, a * v0f);
    C1 = fmaf(fg, C1, a * v1f);
    C2 = fmaf(fg, C2, a * v2f);
    C3 = fmaf(fg, C3, a * v3f);
    n0 = fmaf(fg, n0, ig * k0f);
    n1 = fmaf(fg, n1, ig * k1f);
    n2 = fmaf(fg, n2, ig * k2f);
    n3 = fmaf(fg, n3, ig * k3f);
    float cq = fmaf(C3, q3f, fmaf(C2, q2f, fmaf(C1, q1f, C0 * q0f)));
    float dn = fmaf(n3, q3f, fmaf(n2, q2f, fmaf(n1, q1f, n0 * q0f)));
    cq += __shfl_xor(cq, 16, 64);
    cq += __shfl_xor(cq, 32, 64);
    dn += __shfl_xor(dn, 16, 64);
    dn += __shfl_xor(dn, 32, 64);
    const float denom = fmaxf(fabsf(dn), 1.0f);
    if (dg == 0) hout[base0 + (size_t)t * Dq + e] = f2b(cq / denom);
    ke_c = ke_n; ku_c = ku_n; qu_c = qu_n; vu_c = vu_n; it_c = it_n; ft_c = ft_n;
  }
}

extern "C" void kernel_launch(void* const* d_in, const int* in_sizes, int n_in,
                              void* d_out, int out_size, void* d_ws, size_t ws_size,
                              hipStream_t stream) {
  const void* x     = d_in[0];
  const void* gamma = d_in[1];
  const void* beta  = d_in[2];
  const void* qw    = d_in[3];
  const void* qbv   = d_in[4];
  const void* kw    = d_in[5];
  const void* kbv   = d_in[6];
  const void* vw    = d_in[7];
  const void* vbv   = d_in[8];
  const void* ow    = d_in[9];
  const void* obv   = d_in[10];
  const void* iw    = d_in[11];
  const void* ibv   = d_in[12];
  const void* fw    = d_in[13];
  const void* fbv   = d_in[14];

  const size_t bufBytes = (size_t)Mq * Dq * 2;        // 64 MiB
  const size_t gateBytes = (size_t)Mq * Hq * 4;       // 8 MiB
  const size_t need = 4 * bufBytes + 2 * gateBytes + 4096;
  if (ws_size < need) {   // diagnostic: absmax ~= 1000 signals this branch
    sentinel_kernel<<<(out_size + 255) / 256, 256, 0, stream>>>((unsigned short*)d_out, out_size);
    return;
  }

  char* ws = (char*)d_ws;
  unsigned short* xnb = (unsigned short*)ws; ws += bufBytes;   // reused as hbf
  unsigned short* qbf = (unsigned short*)ws; ws += bufBytes;
  unsigned short* kbf = (unsigned short*)ws; ws += bufBytes;
  unsigned short* vbf = (unsigned short*)ws; ws += bufBytes;
  float* itb = (float*)ws; ws += gateBytes;
  float* ftb = (float*)ws; ws += gateBytes;
  unsigned int* flagp = (unsigned int*)ws;
  unsigned short* hbf = xnb;  // alias: xn dead after the 5 projection GEMMs

  classify_kernel<<<1, 256, 0, stream>>>((const unsigned short*)qw, flagp);
  ln_kernel<<<Mq, 256, 0, stream>>>(x, gamma, beta, xnb, flagp);
  gemm_bt<<<dim3(Mq / 128, 8), 256, 0, stream>>>(xnb, qw, qbv, nullptr, qbf, Dq, Dq, 1.0f,  0, flagp);
  gemm_bt<<<dim3(Mq / 128, 8), 256, 0, stream>>>(xnb, kw, kbv, nullptr, kbf, Dq, Dq, 0.25f, 0, flagp); // /sqrt(16)
  gemm_bt<<<dim3(Mq / 128, 8), 256, 0, stream>>>(xnb, vw, vbv, nullptr, vbf, Dq, Dq, 1.0f,  0, flagp);
  gemm_bt<<<dim3(Mq / 128, 1), 256, 0, stream>>>(xnb, iw, ibv, nullptr, itb, Hq, Dq, 1.0f,  1, flagp);
  gemm_bt<<<dim3(Mq / 128, 1), 256, 0, stream>>>(xnb, fw, fbv, nullptr, ftb, Hq, Dq, 1.0f,  1, flagp);
  scan_kernel<<<Bq * Hq, 64, 0, stream>>>(qbf, kbf, vbf, itb, ftb, hbf);
  gemm_bt<<<dim3(Mq / 128, 8), 256, 0, stream>>>(hbf, ow, obv, x, d_out, Dq, Dq, 1.0f, 2, flagp);
}